// Round 10
// baseline (894.927 us; speedup 1.0000x reference)
//
#include <hip/hip_runtime.h>
#include <hip/hip_bf16.h>

#define DIM 128
#define LVL 8

typedef unsigned int u32;
typedef unsigned short u16;

using bf16x8 = __attribute__((ext_vector_type(8))) short;
using f32x4  = __attribute__((ext_vector_type(4))) float;

__device__ __forceinline__ float bf2f(u16 u) { union { u32 i; float f; } v; v.i = ((u32)u) << 16; return v.f; }
__device__ __forceinline__ u16 f2bf(float f) { __hip_bfloat16 b = __float2bfloat16(f); return *reinterpret_cast<u16*>(&b); }
__device__ __forceinline__ u32 pk2(float lo, float hi) { return (u32)f2bf(lo) | ((u32)f2bf(hi) << 16); }
__device__ __forceinline__ float sigf(float x) { return 1.f / (1.f + __expf(-x)); }
__device__ __forceinline__ float tanhfast(float x) { return 1.f - 2.f / (__expf(2.f * x) + 1.f); }

// ---- level offsets + root fan-in ----
__global__ void k_levels(const int* __restrict__ depth, int n, int* __restrict__ ofs, int* __restrict__ deg) {
  int d = threadIdx.x;
  if (d <= LVL) {
    int lo = 0, hi = n;
    while (lo < hi) { int mid = (lo + hi) >> 1; if (depth[mid] < d) lo = mid + 1; else hi = mid; }
    ofs[d] = lo;
  }
  __syncthreads();
  if (d == 0) deg[0] = ofs[2] - ofs[1];
}

// ---- fan-in counts for non-root parents ----
__global__ void k_mark(const int* __restrict__ parent, const int* __restrict__ depth, int n,
                       int* __restrict__ deg) {
  int j = blockIdx.x * blockDim.x + threadIdx.x;
  if (j >= n) return;
  if (depth[j] < 2) return;
  int p = parent[j];
  if (p >= 0 && p < n) atomicAdd(&deg[p], 1);
}

// ---- per-level compacted lists of NON-LEAF rows (depth>=1) ----
__global__ void k_compact(const int* __restrict__ depth, const int* __restrict__ deg,
                          const int* __restrict__ ofs, int n,
                          int* __restrict__ lcnt, int* __restrict__ plist) {
  int j = blockIdx.x * 256 + threadIdx.x;
  if (j >= n || j == 0) return;
  if (deg[j] == 0) return;
  int d = depth[j];
  int slot = atomicAdd(&lcnt[d], 1);
  plist[ofs[d] + slot] = j;
}

// ---- zero hsum/fcsum rows that receive atomic accumulation (deg>=2) ----
__global__ void k_zero(const int* __restrict__ deg, int n, float* __restrict__ hsum, float* __restrict__ fcsum) {
  int row = blockIdx.x * 4 + (threadIdx.x >> 6);
  if (row >= n) return;
  if (deg[row] < 2) return;
  int l = threadIdx.x & 63;
  float2 z; z.x = 0.f; z.y = 0.f;
  *(float2*)(hsum + (size_t)row * DIM + l * 2) = z;
  *(float2*)(fcsum + (size_t)row * DIM + l * 2) = z;
}

// ---- bf16 weights:
// WcT[640][128]  : natural-k transposed cols of [Wioux|Wfx|Wfh] (k_big staging)
// WallIou[384][128]: LDS image of Wiouh^T, k-PERMUTED (natural k = perm(j)=(j&7)*16+(j>>3)),
//                    XOR-swizzled u16 slot = j ^ ((c&7)<<3)
// WfhTp[128][128]: Wfh^T, k-permuted, linear
__global__ void k_prep(const float* __restrict__ Wioux, const float* __restrict__ Wiouh,
                       const float* __restrict__ Wfx, const float* __restrict__ Wfh,
                       u16* __restrict__ WcT, u16* __restrict__ WallIou, u16* __restrict__ WfhTp) {
  int i = blockIdx.x * 256 + threadIdx.x;
  if (i >= 1152 * 128) return;
  int c = i >> 7, k = i & 127;
  if (c < 640) {
    float v;
    if (c < 384)      v = Wioux[(size_t)k * 384 + c];
    else if (c < 512) v = Wfx[(size_t)k * 128 + (c - 384)];
    else              v = Wfh[(size_t)k * 128 + (c - 512)];
    WcT[(size_t)c * 128 + k] = f2bf(v);
  } else if (c < 1024) {
    int cc = c - 640;
    int kp = (k & 7) * 16 + (k >> 3);
    WallIou[(size_t)cc * 128 + (k ^ ((cc & 7) << 3))] = f2bf(Wiouh[(size_t)kp * 384 + cc]);
  } else {
    int cc = c - 1024;
    int kp = (k & 7) * 16 + (k >> 3);
    WfhTp[(size_t)cc * 128 + k] = f2bf(Wfh[(size_t)kp * 128 + cc]);
  }
}

// ---- x @ [Wioux|Wfx|Wfh] (MFMA bf16): xi chunks 0-3 for parents, xfh (chunk 4) for leaves ----
__global__ __launch_bounds__(256) void k_big(const float* __restrict__ x, const u16* __restrict__ WcT,
                                             const int* __restrict__ deg, u16* __restrict__ xi,
                                             u16* __restrict__ xfh, int n) {
  __shared__ __align__(16) char smem[16384 + 32768];
  char* xsb = smem;
  char* wtb = smem + 16384;
  __shared__ int flg[64];                 // 1=parent 2=leaf 0=invalid
  __shared__ int s_anyP, s_anyL;
  int tid = threadIdx.x;
  int wave = tid >> 6, lane = tid & 63, m = lane & 15, kg = lane >> 4;
  int row0 = blockIdx.x * 64;
  if (row0 >= n) return;
  if (tid < 64) flg[tid] = (row0 + tid < n) ? ((deg[row0 + tid] > 0) ? 1 : 2) : 0;
  __syncthreads();
  if (tid == 0) {
    int ap = 0, al = 0;
    for (int r = 0; r < 64; ++r) { ap |= (flg[r] == 1); al |= (flg[r] == 2); }
    s_anyP = ap; s_anyL = al;
  }
  for (int i = tid; i < 64 * 16; i += 256) {
    int r = i >> 4, c8 = (i & 15) * 8;
    int gr = row0 + r;
    uint4 o = make_uint4(0u, 0u, 0u, 0u);
    if (gr < n) {
      float4 a = *(const float4*)(x + (size_t)gr * DIM + c8);
      float4 b = *(const float4*)(x + (size_t)gr * DIM + c8 + 4);
      o = make_uint4(pk2(a.x, a.y), pk2(a.z, a.w), pk2(b.x, b.y), pk2(b.z, b.w));
    }
    *(uint4*)(xsb + r * 256 + ((c8 * 2) ^ ((r & 7) << 4))) = o;
  }
  int arow = wave * 16 + m;
  for (int ci = 0; ci < 5; ++ci) {
    __syncthreads();                      // x/flags ready on first pass; wtb free afterwards
    bool need = (ci < 4) ? (s_anyP != 0) : (s_anyL != 0);
    if (!need) continue;                  // block-uniform
    for (int i = tid; i < 128 * 16; i += 256) {
      int cl = i >> 4, k8 = (i & 15) * 8;
      uint4 v = *(const uint4*)(WcT + (size_t)(ci * 128 + cl) * 128 + k8);
      *(uint4*)(wtb + cl * 256 + ((k8 * 2) ^ ((cl & 7) << 4))) = v;
    }
    __syncthreads();
    f32x4 acc[8];
    #pragma unroll
    for (int nt = 0; nt < 8; ++nt) acc[nt] = (f32x4){0.f, 0.f, 0.f, 0.f};
    #pragma unroll
    for (int kk = 0; kk < 4; ++kk) {
      int kbyte = kk * 64 + kg * 16;
      bf16x8 a = *(const bf16x8*)(xsb + arow * 256 + (kbyte ^ ((arow & 7) << 4)));
      #pragma unroll
      for (int nt = 0; nt < 8; ++nt) {
        int col = nt * 16 + m;
        bf16x8 b = *(const bf16x8*)(wtb + col * 256 + (kbyte ^ ((col & 7) << 4)));
        acc[nt] = __builtin_amdgcn_mfma_f32_16x16x32_bf16(a, b, acc[nt], 0, 0, 0);
      }
    }
    #pragma unroll
    for (int r = 0; r < 4; ++r) {
      int rl = wave * 16 + kg * 4 + r;
      int gr = row0 + rl;
      if (gr < n) {
        uint4 o = make_uint4(pk2(acc[0][r], acc[1][r]), pk2(acc[2][r], acc[3][r]),
                             pk2(acc[4][r], acc[5][r]), pk2(acc[6][r], acc[7][r]));
        if (ci < 4) { if (flg[rl] == 1) *(uint4*)(xi + ((size_t)gr * 4 + ci) * 128 + m * 8) = o; }
        else        { if (flg[rl] == 2) *(uint4*)(xfh + (size_t)gr * DIM + m * 8) = o; }
      }
    }
  }
}

// ---- all leaf rows, upfront: h=x, c=tanh(x), scatter (h, f*c) to parent ----
__global__ __launch_bounds__(256) void k_leaf(
    const float* __restrict__ x, const u16* __restrict__ xfh, const u16* __restrict__ xi,
    const int* __restrict__ deg, const int* __restrict__ parent, const int* __restrict__ ofs,
    float* __restrict__ hout, float* hsum, float* fcsum, int n) {
  __shared__ float redh[128], redf[128];
  __shared__ int s_l1;
  int tid = threadIdx.x;
  if (tid < 128) { redh[tid] = 0.f; redf[tid] = 0.f; }
  if (tid == 0) s_l1 = 0;
  __syncthreads();
  int row = blockIdx.x * 64 + (tid >> 2);
  int qq = tid & 3;
  int o1 = ofs[1], o2 = ofs[2];
  bool work = (row < n) && (row > 0) && (deg[row] == 0);
  bool isl1 = false;
  if (work) {
    int p = parent[row];
    int dg = deg[p];
    isl1 = (row >= o1) && (row < o2);     // parent is root
    const u16* xf = xi + ((size_t)p * 4 + 3) * 128;
    const u16* xh = xfh + (size_t)row * DIM;
    #pragma unroll 2
    for (int c4 = 0; c4 < 32; c4 += 4) {
      int col0 = qq * 32 + c4;
      float4 xv4 = *(const float4*)(x + (size_t)row * DIM + col0);
      *(float4*)(hout + (size_t)row * DIM + col0) = xv4;
      #pragma unroll
      for (int e = 0; e < 4; ++e) {
        int col = col0 + e;
        int idx = (col & 15) * 8 + (col >> 4);
        float xv = ((const float*)&xv4)[e];
        float fcv = sigf(bf2f(xf[idx]) + bf2f(xh[idx])) * tanhfast(xv);
        if (isl1) {
          atomicAdd(&redh[idx], xv);
          atomicAdd(&redf[idx], fcv);
        } else if (dg == 1) {
          hsum[(size_t)p * DIM + idx] = xv;
          fcsum[(size_t)p * DIM + idx] = fcv;
        } else {
          atomicAdd(&hsum[(size_t)p * DIM + idx], xv);
          atomicAdd(&fcsum[(size_t)p * DIM + idx], fcv);
        }
      }
    }
  }
  if (isl1 && qq == 0) s_l1 = 1;
  __syncthreads();
  if (s_l1 && tid < 128) {
    atomicAdd(&hsum[tid], redh[tid]);
    atomicAdd(&fcsum[tid], redf[tid]);
  }
}

// ---- per-level non-leaf rows: Wiouh LDS-resident, wave-autonomous 16-row tiles ----
__global__ __launch_bounds__(256) void k_level(
    const u16* __restrict__ WallIou, const u16* __restrict__ WfhTp, const u16* __restrict__ xi,
    const int* __restrict__ deg, const int* __restrict__ parent,
    const int* __restrict__ ofs, const int* __restrict__ lcnt, const int* __restrict__ plist,
    float* __restrict__ hout, float* hsum, float* fcsum, int d) {
  __shared__ __align__(16) char wl[98304];       // 384 x 256B Wiouh^T (swizzled, permuted)
  __shared__ __align__(16) char hsball[16384];   // 4 waves x 16 x 256B
  __shared__ float redh[128], redf[128];
  int cnt = lcnt[d];
  if ((int)blockIdx.x * 64 >= cnt) return;       // whole block idle (before any barrier)
  int tid = threadIdx.x;
  int wid = tid >> 6, lane = tid & 63, m = lane & 15, kg = lane >> 4;
  char* hsb = hsball + wid * 4096;
  for (int i = tid; i < 6144; i += 256) ((uint4*)wl)[i] = ((const uint4*)WallIou)[i];
  if (tid < 128) { redh[tid] = 0.f; redf[tid] = 0.f; }
  int base = ofs[d];
  __syncthreads();                               // wl + red ready

  for (int tb = blockIdx.x; tb * 64 < cnt; tb += (int)gridDim.x) {
    int t = tb * 4 + wid;
    int idv = -1;
    if (lane < 16) {
      int s = t * 16 + lane;
      if (s < cnt) idv = plist[base + s];
    }
    int pv = (lane < 16 && idv >= 0) ? parent[idv] : 0;
    int dgv = (lane < 16 && idv >= 0) ? deg[pv] : 0;
    int idr[4], prr[4], dgr[4];
    #pragma unroll
    for (int r = 0; r < 4; ++r) {
      idr[r] = __shfl(idv, kg * 4 + r, 64);
      prr[r] = __shfl(pv,  kg * 4 + r, 64);
      dgr[r] = __shfl(dgv, kg * 4 + r, 64);
    }
    int id_m = __shfl(idv, m, 64);

    // A fragments from global hsum (j-order f32 -> bf16, no LDS staging)
    bf16x8 afr[4];
    #pragma unroll
    for (int kk = 0; kk < 4; ++kk) {
      union { u32 u[4]; bf16x8 v; } cu;
      cu.u[0] = cu.u[1] = cu.u[2] = cu.u[3] = 0u;
      if (id_m >= 0) {
        const float* hp = hsum + (size_t)id_m * DIM + kk * 32 + kg * 8;
        float4 a = *(const float4*)hp; float4 b = *(const float4*)(hp + 4);
        cu.u[0] = pk2(a.x, a.y); cu.u[1] = pk2(a.z, a.w);
        cu.u[2] = pk2(b.x, b.y); cu.u[3] = pk2(b.z, b.w);
      }
      afr[kk] = cu.v;
    }

    float P[8][4], O[8][4];
    const int cxs[3] = {0, 2, 1};
    #pragma unroll
    for (int phx = 0; phx < 3; ++phx) {
      int cx = cxs[phx];
      f32x4 acc[8];
      #pragma unroll
      for (int nt = 0; nt < 8; ++nt) acc[nt] = (f32x4){0.f, 0.f, 0.f, 0.f};
      #pragma unroll
      for (int kk = 0; kk < 4; ++kk) {
        int kby = kk * 64 + kg * 16;
        #pragma unroll
        for (int nt = 0; nt < 8; ++nt) {
          int brow = cx * 128 + nt * 16 + m;
          bf16x8 b = *(const bf16x8*)(wl + brow * 256 + (kby ^ ((brow & 7) << 4)));
          acc[nt] = __builtin_amdgcn_mfma_f32_16x16x32_bf16(afr[kk], b, acc[nt], 0, 0, 0);
        }
      }
      #pragma unroll
      for (int r = 0; r < 4; ++r) {
        int gc = idr[r] >= 0 ? idr[r] : 0;
        uint4 q = *(const uint4*)(xi + ((size_t)gc * 4 + cx) * 128 + m * 8);
        #pragma unroll
        for (int nt = 0; nt < 8; ++nt) {
          float tt = bf2f(((const u16*)&q)[nt]) + acc[nt][r];
          if (phx == 0)      P[nt][r] = sigf(tt);
          else if (phx == 1) P[nt][r] *= tanhfast(tt);
          else               O[nt][r] = sigf(tt);
        }
      }
    }

    // gates -> h,c ; hout ; h-bf16 into wave-private hsb
    float hv[8][4], cv[8][4];
    #pragma unroll
    for (int r = 0; r < 4; ++r) {
      int rl = kg * 4 + r;
      int id = idr[r];
      int gc = id >= 0 ? id : 0;
      float4 fa = *(const float4*)(fcsum + (size_t)gc * DIM + m * 8);
      float4 fb = *(const float4*)(fcsum + (size_t)gc * DIM + m * 8 + 4);
      #pragma unroll
      for (int nt = 0; nt < 8; ++nt) {
        float fcv = (nt < 4) ? ((const float*)&fa)[nt] : ((const float*)&fb)[nt - 4];
        float c_ = fcv + P[nt][r];
        float h_ = O[nt][r] * tanhfast(c_);
        if (id < 0) { c_ = 0.f; h_ = 0.f; }
        cv[nt][r] = c_; hv[nt][r] = h_;
        if (id >= 0) hout[(size_t)id * DIM + nt * 16 + m] = h_;
      }
      uint4 o = make_uint4(pk2(hv[0][r], hv[1][r]), pk2(hv[2][r], hv[3][r]),
                           pk2(hv[4][r], hv[5][r]), pk2(hv[6][r], hv[7][r]));
      *(uint4*)(hsb + rl * 256 + ((m * 16) ^ ((rl & 7) << 4))) = o;
    }

    // f-pre MFMA (A from hsb, B from global WfhTp)
    f32x4 fp[8];
    #pragma unroll
    for (int nt = 0; nt < 8; ++nt) fp[nt] = (f32x4){0.f, 0.f, 0.f, 0.f};
    #pragma unroll
    for (int kk = 0; kk < 4; ++kk) {
      int kby = kk * 64 + kg * 16;
      bf16x8 a = *(const bf16x8*)(hsb + m * 256 + (kby ^ ((m & 7) << 4)));
      #pragma unroll
      for (int nt = 0; nt < 8; ++nt) {
        bf16x8 b = *(const bf16x8*)(WfhTp + (size_t)(nt * 16 + m) * 128 + kk * 32 + kg * 8);
        fp[nt] = __builtin_amdgcn_mfma_f32_16x16x32_bf16(a, b, fp[nt], 0, 0, 0);
      }
    }

    if (d == 1) {
      // all parents = root: wave reduce -> LDS partials (flushed after loop)
      uint4 qf = *(const uint4*)(xi + (size_t)3 * 128 + m * 8);
      float th[8], tf[8];
      #pragma unroll
      for (int nt = 0; nt < 8; ++nt) {
        float sh = 0.f, sf = 0.f;
        #pragma unroll
        for (int r = 0; r < 4; ++r) {
          sh += hv[nt][r];
          sf += (idr[r] >= 0) ? sigf(bf2f(((const u16*)&qf)[nt]) + fp[nt][r]) * cv[nt][r] : 0.f;
        }
        th[nt] = sh; tf[nt] = sf;
      }
      #pragma unroll
      for (int nt = 0; nt < 8; ++nt) {
        th[nt] += __shfl_xor(th[nt], 16, 64); th[nt] += __shfl_xor(th[nt], 32, 64);
        tf[nt] += __shfl_xor(tf[nt], 16, 64); tf[nt] += __shfl_xor(tf[nt], 32, 64);
      }
      if (kg == 0) {
        #pragma unroll
        for (int nt = 0; nt < 8; ++nt) {
          atomicAdd(&redh[m * 8 + nt], th[nt]);
          atomicAdd(&redf[m * 8 + nt], tf[nt]);
        }
      }
    } else {
      #pragma unroll
      for (int r = 0; r < 4; ++r) {
        int id = idr[r];
        if (id < 0) continue;
        int p = prr[r];
        uint4 qf = *(const uint4*)(xi + ((size_t)p * 4 + 3) * 128 + m * 8);
        float fc[8];
        #pragma unroll
        for (int nt = 0; nt < 8; ++nt)
          fc[nt] = sigf(bf2f(((const u16*)&qf)[nt]) + fp[nt][r]) * cv[nt][r];
        if (dgr[r] == 1) {
          *(float4*)(hsum  + (size_t)p * DIM + m * 8)     = make_float4(hv[0][r], hv[1][r], hv[2][r], hv[3][r]);
          *(float4*)(hsum  + (size_t)p * DIM + m * 8 + 4) = make_float4(hv[4][r], hv[5][r], hv[6][r], hv[7][r]);
          *(float4*)(fcsum + (size_t)p * DIM + m * 8)     = make_float4(fc[0], fc[1], fc[2], fc[3]);
          *(float4*)(fcsum + (size_t)p * DIM + m * 8 + 4) = make_float4(fc[4], fc[5], fc[6], fc[7]);
        } else {
          #pragma unroll
          for (int nt = 0; nt < 8; ++nt) {
            atomicAdd(hsum  + (size_t)p * DIM + m * 8 + nt, hv[nt][r]);
            atomicAdd(fcsum + (size_t)p * DIM + m * 8 + nt, fc[nt]);
          }
        }
      }
    }
  }
  if (d == 1) {
    __syncthreads();
    if (tid < 128) {
      atomicAdd(&hsum[tid], redh[tid]);
      atomicAdd(&fcsum[tid], redf[tid]);
    }
  }
}

// ---- root: dense 384-dot with f32 Wiouh, gates ----
__global__ void k_root(const float* __restrict__ x, const float* __restrict__ Wiouh,
                       const u16* __restrict__ xi, const int* __restrict__ deg,
                       const float* __restrict__ hsum, const float* __restrict__ fcsum,
                       float* __restrict__ hout) {
  __shared__ float hsn[128];
  __shared__ float pre[384];
  int tid = threadIdx.x;
  if (deg[0] == 0) { if (tid < 128) hout[tid] = x[tid]; return; }
  if (tid < 128) {
    int kp = (tid & 7) * 16 + (tid >> 3);       // natural k = perm(j)
    hsn[kp] = hsum[tid];
  }
  __syncthreads();
  float a = 0.f;
  #pragma unroll 4
  for (int k = 0; k < 128; ++k) a += hsn[k] * Wiouh[(size_t)k * 384 + tid];
  pre[tid] = a;
  __syncthreads();
  if (tid < 128) {
    int j = tid;
    int c = (j & 7) * 16 + (j >> 3);            // natural col for slot j
    float iv = bf2f(xi[0 * 128 + j]) + pre[c];
    float ov = bf2f(xi[1 * 128 + j]) + pre[128 + c];
    float uv = bf2f(xi[2 * 128 + j]) + pre[256 + c];
    float ci_ = fcsum[j] + sigf(iv) * tanhfast(uv);
    hout[c] = sigf(ov) * tanhfast(ci_);
  }
}

extern "C" void kernel_launch(void* const* d_in, const int* in_sizes, int n_in,
                              void* d_out, int out_size, void* d_ws, size_t ws_size,
                              hipStream_t stream) {
  const float* x    = (const float*)d_in[0];
  const int* parent = (const int*)d_in[1];
  const int* depth  = (const int*)d_in[2];
  const float* Wioux = (const float*)d_in[3];
  const float* Wiouh = (const float*)d_in[4];
  const float* Wfx   = (const float*)d_in[5];
  const float* Wfh   = (const float*)d_in[6];
  int n = in_sizes[0] / DIM;
  float* h = (float*)d_out;

  u16*   WcT     = (u16*)d_ws;                       // 640*128
  u16*   WallIou = WcT + 640 * 128;                  // 384*128 (swizzled LDS image)
  u16*   WfhTp   = WallIou + 384 * 128;              // 128*128 (k-permuted)
  u16*   xi      = WfhTp + 128 * 128;                // n*512 ([v][gate][m][nt])
  u16*   xfh     = xi + (size_t)n * 512;             // n*128 (leaf x@Wfh, C-layout)
  float* hsum    = (float*)(xfh + (size_t)n * DIM);  // n*128 (j-order)
  float* fcsum   = hsum + (size_t)n * DIM;           // n*128 (j-order)
  int*   deg     = (int*)(fcsum + (size_t)n * DIM);  // n
  int*   lcnt    = deg + n;                          // 8
  int*   ofs     = lcnt + 8;                         // LVL+1
  int*   plist   = ofs + (LVL + 1);                  // n

  hipMemsetAsync(deg, 0, (size_t)(n + 8) * sizeof(int), stream);
  k_prep<<<576, 256, 0, stream>>>(Wioux, Wiouh, Wfx, Wfh, WcT, WallIou, WfhTp);
  k_levels<<<1, 32, 0, stream>>>(depth, n, ofs, deg);
  k_mark<<<(n + 255) / 256, 256, 0, stream>>>(parent, depth, n, deg);
  k_compact<<<(n + 255) / 256, 256, 0, stream>>>(depth, deg, ofs, n, lcnt, plist);
  k_zero<<<(n + 3) / 4, 256, 0, stream>>>(deg, n, hsum, fcsum);
  k_big<<<(n + 63) / 64, 256, 0, stream>>>(x, WcT, deg, xi, xfh, n);
  k_leaf<<<(n + 63) / 64, 256, 0, stream>>>(x, xfh, xi, deg, parent, ofs, h, hsum, fcsum, n);

  for (int d = LVL - 2; d >= 1; --d)
    k_level<<<147, 256, 0, stream>>>(WallIou, WfhTp, xi, deg, parent, ofs, lcnt, plist,
                                     h, hsum, fcsum, d);
  k_root<<<1, 384, 0, stream>>>(x, Wiouh, xi, deg, hsum, fcsum, h);
}

// Round 11
// 443.436 us; speedup vs baseline: 2.0182x; 2.0182x over previous
//
#include <hip/hip_runtime.h>
#include <hip/hip_bf16.h>

#define DIM 128
#define LVL 8

typedef unsigned int u32;
typedef unsigned short u16;

using bf16x8 = __attribute__((ext_vector_type(8))) short;
using f32x4  = __attribute__((ext_vector_type(4))) float;

__device__ __forceinline__ float bf2f(u16 u) { union { u32 i; float f; } v; v.i = ((u32)u) << 16; return v.f; }
__device__ __forceinline__ u16 f2bf(float f) { __hip_bfloat16 b = __float2bfloat16(f); return *reinterpret_cast<u16*>(&b); }
__device__ __forceinline__ u32 pk2(float lo, float hi) { return (u32)f2bf(lo) | ((u32)f2bf(hi) << 16); }
__device__ __forceinline__ float sigf(float x) { return 1.f / (1.f + __expf(-x)); }
__device__ __forceinline__ float tanhfast(float x) { return 1.f - 2.f / (__expf(2.f * x) + 1.f); }

// ---- level offsets + root fan-in ----
__global__ void k_levels(const int* __restrict__ depth, int n, int* __restrict__ ofs, int* __restrict__ deg) {
  int d = threadIdx.x;
  if (d <= LVL) {
    int lo = 0, hi = n;
    while (lo < hi) { int mid = (lo + hi) >> 1; if (depth[mid] < d) lo = mid + 1; else hi = mid; }
    ofs[d] = lo;
  }
  __syncthreads();
  if (d == 0) deg[0] = ofs[2] - ofs[1];
}

// ---- fan-in counts for non-root parents ----
__global__ void k_mark(const int* __restrict__ parent, const int* __restrict__ depth, int n,
                       int* __restrict__ deg) {
  int j = blockIdx.x * blockDim.x + threadIdx.x;
  if (j >= n) return;
  if (depth[j] < 2) return;
  int p = parent[j];
  if (p >= 0 && p < n) atomicAdd(&deg[p], 1);
}

// ---- per-level compacted lists of NON-LEAF rows, block-aggregated (no hot atomics) ----
__global__ void k_compact(const int* __restrict__ depth, const int* __restrict__ deg,
                          const int* __restrict__ ofs, int n,
                          int* __restrict__ lcnt, int* __restrict__ plist) {
  __shared__ int lcount[8];
  __shared__ int lbase[8];
  int tid = threadIdx.x;
  if (tid < 8) lcount[tid] = 0;
  __syncthreads();
  int j = blockIdx.x * 256 + tid;
  bool ok = (j < n) && (j > 0) && (deg[j] != 0);
  int d = 0, slot = 0;
  if (ok) {
    d = depth[j];
    slot = atomicAdd(&lcount[d], 1);          // LDS atomic (fast)
  }
  __syncthreads();
  if (tid < 8 && lcount[tid] > 0)
    lbase[tid] = atomicAdd(&lcnt[tid], lcount[tid]);  // <=8 global atomics/block
  __syncthreads();
  if (ok) plist[ofs[d] + lbase[d] + slot] = j;
}

// ---- zero hsum/fcsum rows that receive atomic accumulation (deg>=2) ----
__global__ void k_zero(const int* __restrict__ deg, int n, float* __restrict__ hsum, float* __restrict__ fcsum) {
  int row = blockIdx.x * 4 + (threadIdx.x >> 6);
  if (row >= n) return;
  if (deg[row] < 2) return;
  int l = threadIdx.x & 63;
  float2 z; z.x = 0.f; z.y = 0.f;
  *(float2*)(hsum + (size_t)row * DIM + l * 2) = z;
  *(float2*)(fcsum + (size_t)row * DIM + l * 2) = z;
}

// ---- bf16 weights:
// WcT[640][128]  : natural-k transposed cols of [Wioux|Wfx|Wfh] (k_big staging)
// WallIou[384][128]: LDS image of Wiouh^T, k-PERMUTED (natural k = perm(j)=(j&7)*16+(j>>3)),
//                    XOR-swizzled u16 slot = j ^ ((c&7)<<3)
// WfhTp[128][128]: Wfh^T, k-permuted, linear
__global__ void k_prep(const float* __restrict__ Wioux, const float* __restrict__ Wiouh,
                       const float* __restrict__ Wfx, const float* __restrict__ Wfh,
                       u16* __restrict__ WcT, u16* __restrict__ WallIou, u16* __restrict__ WfhTp) {
  int i = blockIdx.x * 256 + threadIdx.x;
  if (i >= 1152 * 128) return;
  int c = i >> 7, k = i & 127;
  if (c < 640) {
    float v;
    if (c < 384)      v = Wioux[(size_t)k * 384 + c];
    else if (c < 512) v = Wfx[(size_t)k * 128 + (c - 384)];
    else              v = Wfh[(size_t)k * 128 + (c - 512)];
    WcT[(size_t)c * 128 + k] = f2bf(v);
  } else if (c < 1024) {
    int cc = c - 640;
    int kp = (k & 7) * 16 + (k >> 3);
    WallIou[(size_t)cc * 128 + (k ^ ((cc & 7) << 3))] = f2bf(Wiouh[(size_t)kp * 384 + cc]);
  } else {
    int cc = c - 1024;
    int kp = (k & 7) * 16 + (k >> 3);
    WfhTp[(size_t)cc * 128 + k] = f2bf(Wfh[(size_t)kp * 128 + cc]);
  }
}

// ---- x @ [Wioux|Wfx|Wfh] (MFMA bf16): xi chunks 0-3 for parents, xfh (chunk 4) for leaves ----
__global__ __launch_bounds__(256) void k_big(const float* __restrict__ x, const u16* __restrict__ WcT,
                                             const int* __restrict__ deg, u16* __restrict__ xi,
                                             u16* __restrict__ xfh, int n) {
  __shared__ __align__(16) char smem[16384 + 32768];
  char* xsb = smem;
  char* wtb = smem + 16384;
  __shared__ int flg[64];                 // 1=parent 2=leaf 0=invalid
  __shared__ int s_anyP, s_anyL;
  int tid = threadIdx.x;
  int wave = tid >> 6, lane = tid & 63, m = lane & 15, kg = lane >> 4;
  int row0 = blockIdx.x * 64;
  if (row0 >= n) return;
  if (tid < 64) flg[tid] = (row0 + tid < n) ? ((deg[row0 + tid] > 0) ? 1 : 2) : 0;
  __syncthreads();
  if (tid == 0) {
    int ap = 0, al = 0;
    for (int r = 0; r < 64; ++r) { ap |= (flg[r] == 1); al |= (flg[r] == 2); }
    s_anyP = ap; s_anyL = al;
  }
  for (int i = tid; i < 64 * 16; i += 256) {
    int r = i >> 4, c8 = (i & 15) * 8;
    int gr = row0 + r;
    uint4 o = make_uint4(0u, 0u, 0u, 0u);
    if (gr < n) {
      float4 a = *(const float4*)(x + (size_t)gr * DIM + c8);
      float4 b = *(const float4*)(x + (size_t)gr * DIM + c8 + 4);
      o = make_uint4(pk2(a.x, a.y), pk2(a.z, a.w), pk2(b.x, b.y), pk2(b.z, b.w));
    }
    *(uint4*)(xsb + r * 256 + ((c8 * 2) ^ ((r & 7) << 4))) = o;
  }
  int arow = wave * 16 + m;
  for (int ci = 0; ci < 5; ++ci) {
    __syncthreads();                      // x/flags ready on first pass; wtb free afterwards
    bool need = (ci < 4) ? (s_anyP != 0) : (s_anyL != 0);
    if (!need) continue;                  // block-uniform
    for (int i = tid; i < 128 * 16; i += 256) {
      int cl = i >> 4, k8 = (i & 15) * 8;
      uint4 v = *(const uint4*)(WcT + (size_t)(ci * 128 + cl) * 128 + k8);
      *(uint4*)(wtb + cl * 256 + ((k8 * 2) ^ ((cl & 7) << 4))) = v;
    }
    __syncthreads();
    f32x4 acc[8];
    #pragma unroll
    for (int nt = 0; nt < 8; ++nt) acc[nt] = (f32x4){0.f, 0.f, 0.f, 0.f};
    #pragma unroll
    for (int kk = 0; kk < 4; ++kk) {
      int kbyte = kk * 64 + kg * 16;
      bf16x8 a = *(const bf16x8*)(xsb + arow * 256 + (kbyte ^ ((arow & 7) << 4)));
      #pragma unroll
      for (int nt = 0; nt < 8; ++nt) {
        int col = nt * 16 + m;
        bf16x8 b = *(const bf16x8*)(wtb + col * 256 + (kbyte ^ ((col & 7) << 4)));
        acc[nt] = __builtin_amdgcn_mfma_f32_16x16x32_bf16(a, b, acc[nt], 0, 0, 0);
      }
    }
    #pragma unroll
    for (int r = 0; r < 4; ++r) {
      int rl = wave * 16 + kg * 4 + r;
      int gr = row0 + rl;
      if (gr < n) {
        uint4 o = make_uint4(pk2(acc[0][r], acc[1][r]), pk2(acc[2][r], acc[3][r]),
                             pk2(acc[4][r], acc[5][r]), pk2(acc[6][r], acc[7][r]));
        if (ci < 4) { if (flg[rl] == 1) *(uint4*)(xi + ((size_t)gr * 4 + ci) * 128 + m * 8) = o; }
        else        { if (flg[rl] == 2) *(uint4*)(xfh + (size_t)gr * DIM + m * 8) = o; }
      }
    }
  }
}

// ---- all leaf rows, upfront: h=x, c=tanh(x), scatter (h, f*c) to parent ----
__global__ __launch_bounds__(256) void k_leaf(
    const float* __restrict__ x, const u16* __restrict__ xfh, const u16* __restrict__ xi,
    const int* __restrict__ deg, const int* __restrict__ parent, const int* __restrict__ ofs,
    float* __restrict__ hout, float* hsum, float* fcsum, int n) {
  __shared__ float redh[128], redf[128];
  __shared__ int s_l1;
  int tid = threadIdx.x;
  if (tid < 128) { redh[tid] = 0.f; redf[tid] = 0.f; }
  if (tid == 0) s_l1 = 0;
  __syncthreads();
  int row = blockIdx.x * 64 + (tid >> 2);
  int qq = tid & 3;
  int o1 = ofs[1], o2 = ofs[2];
  bool work = (row < n) && (row > 0) && (deg[row] == 0);
  bool isl1 = false;
  if (work) {
    int p = parent[row];
    int dg = deg[p];
    isl1 = (row >= o1) && (row < o2);     // parent is root
    const u16* xf = xi + ((size_t)p * 4 + 3) * 128;
    const u16* xh = xfh + (size_t)row * DIM;
    #pragma unroll 2
    for (int c4 = 0; c4 < 32; c4 += 4) {
      int col0 = qq * 32 + c4;
      float4 xv4 = *(const float4*)(x + (size_t)row * DIM + col0);
      *(float4*)(hout + (size_t)row * DIM + col0) = xv4;
      #pragma unroll
      for (int e = 0; e < 4; ++e) {
        int col = col0 + e;
        int idx = (col & 15) * 8 + (col >> 4);
        float xv = ((const float*)&xv4)[e];
        float fcv = sigf(bf2f(xf[idx]) + bf2f(xh[idx])) * tanhfast(xv);
        if (isl1) {
          atomicAdd(&redh[idx], xv);
          atomicAdd(&redf[idx], fcv);
        } else if (dg == 1) {
          hsum[(size_t)p * DIM + idx] = xv;
          fcsum[(size_t)p * DIM + idx] = fcv;
        } else {
          atomicAdd(&hsum[(size_t)p * DIM + idx], xv);
          atomicAdd(&fcsum[(size_t)p * DIM + idx], fcv);
        }
      }
    }
  }
  if (isl1 && qq == 0) s_l1 = 1;
  __syncthreads();
  if (s_l1 && tid < 128) {
    atomicAdd(&hsum[tid], redh[tid]);
    atomicAdd(&fcsum[tid], redf[tid]);
  }
}

// ---- per-level non-leaf rows: Wiouh LDS-resident, wave-autonomous 16-row tiles ----
__global__ __launch_bounds__(256) void k_level(
    const u16* __restrict__ WallIou, const u16* __restrict__ WfhTp, const u16* __restrict__ xi,
    const int* __restrict__ deg, const int* __restrict__ parent,
    const int* __restrict__ ofs, const int* __restrict__ lcnt, const int* __restrict__ plist,
    float* __restrict__ hout, float* hsum, float* fcsum, int d) {
  __shared__ __align__(16) char wl[98304];       // 384 x 256B Wiouh^T (swizzled, permuted)
  __shared__ __align__(16) char hsball[16384];   // 4 waves x 16 x 256B
  __shared__ float redh[128], redf[128];
  int cnt = lcnt[d];
  if ((int)blockIdx.x * 64 >= cnt) return;       // whole block idle (before any barrier)
  int tid = threadIdx.x;
  int wid = tid >> 6, lane = tid & 63, m = lane & 15, kg = lane >> 4;
  char* hsb = hsball + wid * 4096;
  for (int i = tid; i < 6144; i += 256) ((uint4*)wl)[i] = ((const uint4*)WallIou)[i];
  if (tid < 128) { redh[tid] = 0.f; redf[tid] = 0.f; }
  int base = ofs[d];
  __syncthreads();                               // wl + red ready

  for (int tb = blockIdx.x; tb * 64 < cnt; tb += (int)gridDim.x) {
    int t = tb * 4 + wid;
    int idv = -1;
    if (lane < 16) {
      int s = t * 16 + lane;
      if (s < cnt) idv = plist[base + s];
    }
    int pv = (lane < 16 && idv >= 0) ? parent[idv] : 0;
    int dgv = (lane < 16 && idv >= 0) ? deg[pv] : 0;
    int idr[4], prr[4], dgr[4];
    #pragma unroll
    for (int r = 0; r < 4; ++r) {
      idr[r] = __shfl(idv, kg * 4 + r, 64);
      prr[r] = __shfl(pv,  kg * 4 + r, 64);
      dgr[r] = __shfl(dgv, kg * 4 + r, 64);
    }
    int id_m = __shfl(idv, m, 64);

    // A fragments from global hsum (j-order f32 -> bf16, no LDS staging)
    bf16x8 afr[4];
    #pragma unroll
    for (int kk = 0; kk < 4; ++kk) {
      union { u32 u[4]; bf16x8 v; } cu;
      cu.u[0] = cu.u[1] = cu.u[2] = cu.u[3] = 0u;
      if (id_m >= 0) {
        const float* hp = hsum + (size_t)id_m * DIM + kk * 32 + kg * 8;
        float4 a = *(const float4*)hp; float4 b = *(const float4*)(hp + 4);
        cu.u[0] = pk2(a.x, a.y); cu.u[1] = pk2(a.z, a.w);
        cu.u[2] = pk2(b.x, b.y); cu.u[3] = pk2(b.z, b.w);
      }
      afr[kk] = cu.v;
    }

    float P[8][4], O[8][4];
    const int cxs[3] = {0, 2, 1};
    #pragma unroll
    for (int phx = 0; phx < 3; ++phx) {
      int cx = cxs[phx];
      f32x4 acc[8];
      #pragma unroll
      for (int nt = 0; nt < 8; ++nt) acc[nt] = (f32x4){0.f, 0.f, 0.f, 0.f};
      #pragma unroll
      for (int kk = 0; kk < 4; ++kk) {
        int kby = kk * 64 + kg * 16;
        #pragma unroll
        for (int nt = 0; nt < 8; ++nt) {
          int brow = cx * 128 + nt * 16 + m;
          bf16x8 b = *(const bf16x8*)(wl + brow * 256 + (kby ^ ((brow & 7) << 4)));
          acc[nt] = __builtin_amdgcn_mfma_f32_16x16x32_bf16(afr[kk], b, acc[nt], 0, 0, 0);
        }
      }
      #pragma unroll
      for (int r = 0; r < 4; ++r) {
        int gc = idr[r] >= 0 ? idr[r] : 0;
        uint4 q = *(const uint4*)(xi + ((size_t)gc * 4 + cx) * 128 + m * 8);
        #pragma unroll
        for (int nt = 0; nt < 8; ++nt) {
          float tt = bf2f(((const u16*)&q)[nt]) + acc[nt][r];
          if (phx == 0)      P[nt][r] = sigf(tt);
          else if (phx == 1) P[nt][r] *= tanhfast(tt);
          else               O[nt][r] = sigf(tt);
        }
      }
    }

    // gates -> h,c ; hout ; h-bf16 into wave-private hsb
    float hv[8][4], cv[8][4];
    #pragma unroll
    for (int r = 0; r < 4; ++r) {
      int rl = kg * 4 + r;
      int id = idr[r];
      int gc = id >= 0 ? id : 0;
      float4 fa = *(const float4*)(fcsum + (size_t)gc * DIM + m * 8);
      float4 fb = *(const float4*)(fcsum + (size_t)gc * DIM + m * 8 + 4);
      #pragma unroll
      for (int nt = 0; nt < 8; ++nt) {
        float fcv = (nt < 4) ? ((const float*)&fa)[nt] : ((const float*)&fb)[nt - 4];
        float c_ = fcv + P[nt][r];
        float h_ = O[nt][r] * tanhfast(c_);
        if (id < 0) { c_ = 0.f; h_ = 0.f; }
        cv[nt][r] = c_; hv[nt][r] = h_;
        if (id >= 0) hout[(size_t)id * DIM + nt * 16 + m] = h_;
      }
      uint4 o = make_uint4(pk2(hv[0][r], hv[1][r]), pk2(hv[2][r], hv[3][r]),
                           pk2(hv[4][r], hv[5][r]), pk2(hv[6][r], hv[7][r]));
      *(uint4*)(hsb + rl * 256 + ((m * 16) ^ ((rl & 7) << 4))) = o;
    }

    // f-pre MFMA (A from hsb, B from global WfhTp)
    f32x4 fp[8];
    #pragma unroll
    for (int nt = 0; nt < 8; ++nt) fp[nt] = (f32x4){0.f, 0.f, 0.f, 0.f};
    #pragma unroll
    for (int kk = 0; kk < 4; ++kk) {
      int kby = kk * 64 + kg * 16;
      bf16x8 a = *(const bf16x8*)(hsb + m * 256 + (kby ^ ((m & 7) << 4)));
      #pragma unroll
      for (int nt = 0; nt < 8; ++nt) {
        bf16x8 b = *(const bf16x8*)(WfhTp + (size_t)(nt * 16 + m) * 128 + kk * 32 + kg * 8);
        fp[nt] = __builtin_amdgcn_mfma_f32_16x16x32_bf16(a, b, fp[nt], 0, 0, 0);
      }
    }

    if (d == 1) {
      // all parents = root: wave reduce -> LDS partials (flushed after loop)
      uint4 qf = *(const uint4*)(xi + (size_t)3 * 128 + m * 8);
      float th[8], tf[8];
      #pragma unroll
      for (int nt = 0; nt < 8; ++nt) {
        float sh = 0.f, sf = 0.f;
        #pragma unroll
        for (int r = 0; r < 4; ++r) {
          sh += hv[nt][r];
          sf += (idr[r] >= 0) ? sigf(bf2f(((const u16*)&qf)[nt]) + fp[nt][r]) * cv[nt][r] : 0.f;
        }
        th[nt] = sh; tf[nt] = sf;
      }
      #pragma unroll
      for (int nt = 0; nt < 8; ++nt) {
        th[nt] += __shfl_xor(th[nt], 16, 64); th[nt] += __shfl_xor(th[nt], 32, 64);
        tf[nt] += __shfl_xor(tf[nt], 16, 64); tf[nt] += __shfl_xor(tf[nt], 32, 64);
      }
      if (kg == 0) {
        #pragma unroll
        for (int nt = 0; nt < 8; ++nt) {
          atomicAdd(&redh[m * 8 + nt], th[nt]);
          atomicAdd(&redf[m * 8 + nt], tf[nt]);
        }
      }
    } else {
      #pragma unroll
      for (int r = 0; r < 4; ++r) {
        int id = idr[r];
        if (id < 0) continue;
        int p = prr[r];
        uint4 qf = *(const uint4*)(xi + ((size_t)p * 4 + 3) * 128 + m * 8);
        float fc[8];
        #pragma unroll
        for (int nt = 0; nt < 8; ++nt)
          fc[nt] = sigf(bf2f(((const u16*)&qf)[nt]) + fp[nt][r]) * cv[nt][r];
        if (dgr[r] == 1) {
          *(float4*)(hsum  + (size_t)p * DIM + m * 8)     = make_float4(hv[0][r], hv[1][r], hv[2][r], hv[3][r]);
          *(float4*)(hsum  + (size_t)p * DIM + m * 8 + 4) = make_float4(hv[4][r], hv[5][r], hv[6][r], hv[7][r]);
          *(float4*)(fcsum + (size_t)p * DIM + m * 8)     = make_float4(fc[0], fc[1], fc[2], fc[3]);
          *(float4*)(fcsum + (size_t)p * DIM + m * 8 + 4) = make_float4(fc[4], fc[5], fc[6], fc[7]);
        } else {
          #pragma unroll
          for (int nt = 0; nt < 8; ++nt) {
            atomicAdd(hsum  + (size_t)p * DIM + m * 8 + nt, hv[nt][r]);
            atomicAdd(fcsum + (size_t)p * DIM + m * 8 + nt, fc[nt]);
          }
        }
      }
    }
  }
  if (d == 1) {
    __syncthreads();
    if (tid < 128) {
      atomicAdd(&hsum[tid], redh[tid]);
      atomicAdd(&fcsum[tid], redf[tid]);
    }
  }
}

// ---- root: dense 384-dot with f32 Wiouh, gates ----
__global__ void k_root(const float* __restrict__ x, const float* __restrict__ Wiouh,
                       const u16* __restrict__ xi, const int* __restrict__ deg,
                       const float* __restrict__ hsum, const float* __restrict__ fcsum,
                       float* __restrict__ hout) {
  __shared__ float hsn[128];
  __shared__ float pre[384];
  int tid = threadIdx.x;
  if (deg[0] == 0) { if (tid < 128) hout[tid] = x[tid]; return; }
  if (tid < 128) {
    int kp = (tid & 7) * 16 + (tid >> 3);       // natural k = perm(j)
    hsn[kp] = hsum[tid];
  }
  __syncthreads();
  float a = 0.f;
  #pragma unroll 4
  for (int k = 0; k < 128; ++k) a += hsn[k] * Wiouh[(size_t)k * 384 + tid];
  pre[tid] = a;
  __syncthreads();
  if (tid < 128) {
    int j = tid;
    int c = (j & 7) * 16 + (j >> 3);            // natural col for slot j
    float iv = bf2f(xi[0 * 128 + j]) + pre[c];
    float ov = bf2f(xi[1 * 128 + j]) + pre[128 + c];
    float uv = bf2f(xi[2 * 128 + j]) + pre[256 + c];
    float ci_ = fcsum[j] + sigf(iv) * tanhfast(uv);
    hout[c] = sigf(ov) * tanhfast(ci_);
  }
}

extern "C" void kernel_launch(void* const* d_in, const int* in_sizes, int n_in,
                              void* d_out, int out_size, void* d_ws, size_t ws_size,
                              hipStream_t stream) {
  const float* x    = (const float*)d_in[0];
  const int* parent = (const int*)d_in[1];
  const int* depth  = (const int*)d_in[2];
  const float* Wioux = (const float*)d_in[3];
  const float* Wiouh = (const float*)d_in[4];
  const float* Wfx   = (const float*)d_in[5];
  const float* Wfh   = (const float*)d_in[6];
  int n = in_sizes[0] / DIM;
  float* h = (float*)d_out;

  u16*   WcT     = (u16*)d_ws;                       // 640*128
  u16*   WallIou = WcT + 640 * 128;                  // 384*128 (swizzled LDS image)
  u16*   WfhTp   = WallIou + 384 * 128;              // 128*128 (k-permuted)
  u16*   xi      = WfhTp + 128 * 128;                // n*512 ([v][gate][m][nt])
  u16*   xfh     = xi + (size_t)n * 512;             // n*128 (leaf x@Wfh, C-layout)
  float* hsum    = (float*)(xfh + (size_t)n * DIM);  // n*128 (j-order)
  float* fcsum   = hsum + (size_t)n * DIM;           // n*128 (j-order)
  int*   deg     = (int*)(fcsum + (size_t)n * DIM);  // n
  int*   lcnt    = deg + n;                          // 8
  int*   ofs     = lcnt + 8;                         // LVL+1
  int*   plist   = ofs + (LVL + 1);                  // n

  hipMemsetAsync(deg, 0, (size_t)(n + 8) * sizeof(int), stream);
  k_prep<<<576, 256, 0, stream>>>(Wioux, Wiouh, Wfx, Wfh, WcT, WallIou, WfhTp);
  k_levels<<<1, 32, 0, stream>>>(depth, n, ofs, deg);
  k_mark<<<(n + 255) / 256, 256, 0, stream>>>(parent, depth, n, deg);
  k_compact<<<(n + 255) / 256, 256, 0, stream>>>(depth, deg, ofs, n, lcnt, plist);
  k_zero<<<(n + 3) / 4, 256, 0, stream>>>(deg, n, hsum, fcsum);
  k_big<<<(n + 63) / 64, 256, 0, stream>>>(x, WcT, deg, xi, xfh, n);
  k_leaf<<<(n + 63) / 64, 256, 0, stream>>>(x, xfh, xi, deg, parent, ofs, h, hsum, fcsum, n);

  for (int d = LVL - 2; d >= 1; --d)
    k_level<<<147, 256, 0, stream>>>(WallIou, WfhTp, xi, deg, parent, ofs, lcnt, plist,
                                     h, hsum, fcsum, d);
  k_root<<<1, 384, 0, stream>>>(x, Wiouh, xi, deg, hsum, fcsum, h);
}